// Round 5
// baseline (552.935 us; speedup 1.0000x reference)
//
#include <hip/hip_runtime.h>
#include <math.h>

// ---------------------------------------------------------------------------
#define B_ROWS   8192
#define NZ       100
#define NC       2
#define H1       256
#define H2       64
#define FEATN    8192
#define FDIM     1024
#define RROWS    8             // rows per k_main block
#define FF       8             // f values per thread
#define CHUNKF   (256 * FF)    // 2048 f per chunk
#define NCHUNK   (FEATN / CHUNKF)  // 4
#define SLABS    64            // row slabs for stats stage 1

// ---------------------------------------------------------------------------
// JAX threefry2x32, partitionable, key=(0,42), counter=(0, flat)
__device__ __forceinline__ unsigned rotl32(unsigned v, int r) {
    return (v << r) | (v >> (32 - r));
}
__device__ __forceinline__ unsigned threefry_bits(unsigned lo) {
    const unsigned ks0 = 0u, ks1 = 42u, ks2 = 0x1BD11BDAu ^ 42u;
    unsigned x0 = 0u + ks0;
    unsigned x1 = lo + ks1;
#define TF_R4(a,b,c,d) \
    x0 += x1; x1 = rotl32(x1,a); x1 ^= x0; \
    x0 += x1; x1 = rotl32(x1,b); x1 ^= x0; \
    x0 += x1; x1 = rotl32(x1,c); x1 ^= x0; \
    x0 += x1; x1 = rotl32(x1,d); x1 ^= x0;
    TF_R4(13,15,26,6);  x0 += ks1; x1 += ks2 + 1u;
    TF_R4(17,29,16,24); x0 += ks2; x1 += ks0 + 2u;
    TF_R4(13,15,26,6);  x0 += ks0; x1 += ks1 + 3u;
    TF_R4(17,29,16,24); x0 += ks1; x1 += ks2 + 4u;
    TF_R4(13,15,26,6);  x0 += ks2; x1 += ks0 + 5u;
#undef TF_R4
    return x0 ^ x1;
}
__device__ __forceinline__ float gumbel_g(unsigned flat) {
    unsigned bits = threefry_bits(flat);
    float u  = __uint_as_float((bits >> 9) | 0x3f800000u) - 1.0f;
    float U  = 0.001f * u;
    float t1 = U + 0.001f;
    float L1 = (float)log((double)t1);
    float A  = 0.001f - L1;
    float L2 = (float)log((double)A);
    return -L2;
}

// ---------------------------------------------------------------------------
// K1: a1 = concat(x,y) @ W1 + b1, fp64 accumulate
__global__ __launch_bounds__(256) void k_a1(
    const float* __restrict__ x, const float* __restrict__ y,
    const float* __restrict__ W1, const float* __restrict__ b1,
    float* __restrict__ a1)
{
    const int j  = threadIdx.x;
    const int b0 = blockIdx.x * 8;
    double acc[8];
#pragma unroll
    for (int r = 0; r < 8; ++r) acc[r] = 0.0;
    for (int i = 0; i < NZ; ++i) {
        float w = W1[i * H1 + j];
#pragma unroll
        for (int r = 0; r < 8; ++r)
            acc[r] += (double)x[(b0 + r) * NZ + i] * (double)w;
    }
#pragma unroll
    for (int i = 0; i < NC; ++i) {
        float w = W1[(NZ + i) * H1 + j];
#pragma unroll
        for (int r = 0; r < 8; ++r)
            acc[r] += (double)y[(b0 + r) * NC + i] * (double)w;
    }
    double bb = (double)b1[j];
#pragma unroll
    for (int r = 0; r < 8; ++r)
        a1[(b0 + r) * H1 + j] = (float)(acc[r] + bb);
}

// ---------------------------------------------------------------------------
// BN stats, coalesced 2-stage. Stage 1: per-slab per-column fp64 partials.
__global__ __launch_bounds__(256) void k_stats1(
    const float* __restrict__ A, int ncol,
    double* __restrict__ p1, double* __restrict__ p2)
{
    const int g = blockIdx.x, t = threadIdx.x;
    const int c    = t & (ncol - 1);
    const int rsub = t / ncol;
    const int rpt  = 256 / ncol;
    const int rows = B_ROWS / SLABS;          // 128
    const float* base = A + (size_t)g * rows * ncol;
    double s = 0.0, s2 = 0.0;
    for (int r = rsub; r < rows; r += rpt) {
        double v = (double)base[r * ncol + c];   // coalesced
        s += v; s2 += v * v;
    }
    __shared__ double ls[256], ls2[256];
    ls[t] = s; ls2[t] = s2;
    __syncthreads();
    if (rsub == 0) {
        for (int k = 1; k < rpt; ++k) { s += ls[k * ncol + c]; s2 += ls2[k * ncol + c]; }
        p1[g * ncol + c] = s;
        p2[g * ncol + c] = s2;
    }
}

// Stage 2: reduce SLABS partials per column; fold gamma/beta into scale/shift.
__global__ __launch_bounds__(64) void k_stats2(
    const double* __restrict__ p1, const double* __restrict__ p2, int ncol,
    const float* __restrict__ gamma, const float* __restrict__ beta,
    float* __restrict__ scale, float* __restrict__ shift)
{
    const int j = blockIdx.x, t = threadIdx.x;
    double s  = p1[(size_t)t * ncol + j];
    double s2 = p2[(size_t)t * ncol + j];
#pragma unroll
    for (int off = 32; off; off >>= 1) {
        s  += __shfl_xor(s, off);
        s2 += __shfl_xor(s2, off);
    }
    if (t == 0) {
        double mean = s * (1.0 / B_ROWS);
        double var  = s2 * (1.0 / B_ROWS) - mean * mean;
        double rstd = 1.0 / sqrt(var + 1e-5);
        double sc   = (double)gamma[j] * rstd;
        scale[j] = (float)sc;
        shift[j] = (float)((double)beta[j] - mean * sc);
    }
}

// ---------------------------------------------------------------------------
// K3: a2 = relu(bn(a1)) @ W2 + b2, fp64 accumulate
__global__ __launch_bounds__(256) void k_a2(
    const float* __restrict__ a1,
    const float* __restrict__ sc1, const float* __restrict__ sh1,
    const float* __restrict__ W2, const float* __restrict__ b2,
    float* __restrict__ a2)
{
    const int t  = threadIdx.x;
    const int k  = t & 63;
    const int rr = t >> 6;
    const int b  = blockIdx.x * 4 + rr;
    double acc = 0.0;
    for (int j = 0; j < H1; ++j) {
        float h = fmaxf(fmaf(a1[b * H1 + j], sc1[j], sh1[j]), 0.0f);
        acc += (double)h * (double)W2[j * H2 + k];
    }
    a2[b * H2 + k] = (float)(acc + (double)b2[k]);
}

// ---------------------------------------------------------------------------
// k_main helpers: everything scalarized — NO per-thread arrays in hot path.
#define ACC_DECL \
    float4 aA0=bbA,aA1=bbA,aA2=bbA,aA3=bbA,aA4=bbA,aA5=bbA,aA6=bbA,aA7=bbA; \
    float4 aB0=bbB,aB1=bbB,aB2=bbB,aB3=bbB,aB4=bbB,aB5=bbB,aB6=bbB,aB7=bbB;

#define FMA1(r, hr) \
    aA##r.x = fmaf(hr, wA.x, aA##r.x); aA##r.y = fmaf(hr, wA.y, aA##r.y); \
    aA##r.z = fmaf(hr, wA.z, aA##r.z); aA##r.w = fmaf(hr, wA.w, aA##r.w); \
    aB##r.x = fmaf(hr, wB.x, aB##r.x); aB##r.y = fmaf(hr, wB.y, aB##r.y); \
    aB##r.z = fmaf(hr, wB.z, aB##r.z); aB##r.w = fmaf(hr, wB.w, aB##r.w);

#define JBODY \
    { \
        const float4 wA = *(const float4*)(wrow); \
        const float4 wB = *(const float4*)(wrow + 4); \
        const float4 h0 = *(const float4*)(&h2T[j][0]); \
        const float4 h1 = *(const float4*)(&h2T[j][4]); \
        FMA1(0, h0.x) FMA1(1, h0.y) FMA1(2, h0.z) FMA1(3, h0.w) \
        FMA1(4, h1.x) FMA1(5, h1.y) FMA1(6, h1.z) FMA1(7, h1.w) \
        wrow += FEATN; \
    }

#define ROWMAX(r) { \
    float m = fmaxf(fmaxf(fmaxf(aA##r.x, aA##r.y), fmaxf(aA##r.z, aA##r.w)), \
                    fmaxf(fmaxf(aB##r.x, aB##r.y), fmaxf(aB##r.z, aB##r.w))); \
    m = fmaxf(m, __shfl_xor(m, 32)); m = fmaxf(m, __shfl_xor(m, 16)); \
    m = fmaxf(m, __shfl_xor(m, 8));  m = fmaxf(m, __shfl_xor(m, 4)); \
    m = fmaxf(m, __shfl_xor(m, 2));  m = fmaxf(m, __shfl_xor(m, 1)); \
    if (lane == 0) cm[fc][r][wv] = m; }

#define CHK(r, vexpr, q) { \
    float vv = (vexpr); \
    if (vv >= th) { \
        int f = fbase + q; \
        float scv = vv + gumbel_g((unsigned)(b0 + r) * (unsigned)FEATN + (unsigned)f); \
        if (scv > bS##r || (scv == bS##r && f < bI##r)) { bS##r = scv; bI##r = f; } \
    } }

#define CAND(r) if (qmask & (1u << r)) { \
    const float th = thrS[r]; \
    CHK(r, aA##r.x, 0) CHK(r, aA##r.y, 1) CHK(r, aA##r.z, 2) CHK(r, aA##r.w, 3) \
    CHK(r, aB##r.x, 4) CHK(r, aB##r.y, 5) CHK(r, aB##r.z, 6) CHK(r, aB##r.w, 7) }

#define REDROW(r) { \
    float v = bS##r; int ix = bI##r; \
    _Pragma("unroll") \
    for (int off = 32; off; off >>= 1) { \
        float ov = __shfl_xor(v, off); \
        int   oi = __shfl_xor(ix, off); \
        if (ov > v || (ov == v && oi < ix)) { v = ov; ix = oi; } \
    } \
    if (lane == 0) { redS[r][wv] = v; redI[r][wv] = ix; } }

// K5: pass A = rowmax of logits; pass B = recompute only qualifying
//     (chunk,wave) cells with gumbel; gather codebook row.
__global__ __launch_bounds__(256) void k_main(
    const float* __restrict__ a2,
    const float* __restrict__ sc2, const float* __restrict__ sh2,
    const float* __restrict__ W3, const float* __restrict__ b3,
    const float* __restrict__ codebook, float* __restrict__ out)
{
    const int t    = threadIdx.x;
    const int wv   = t >> 6;
    const int lane = t & 63;
    const int b0   = blockIdx.x * RROWS;

    __shared__ __align__(16) float h2T[64][RROWS];   // [j][r], 2 KB
    __shared__ float cm[NCHUNK][RROWS][4];
    __shared__ float thrS[RROWS];
    __shared__ float redS[RROWS][4];
    __shared__ int   redI[RROWS][4];
    __shared__ int   rowInd[RROWS];

    // h2 = relu(bn(a2)) for our rows — strided: 512 elements, 256 threads
    for (int q = t; q < RROWS * 64; q += 256) {
        int j = q >> 3, r = q & 7;          // j in 0..63, r in 0..7
        float v = a2[(b0 + r) * H2 + j];
        h2T[j][r] = fmaxf(fmaf(v, sc2[j], sh2[j]), 0.0f);
    }
    __syncthreads();

    // ---- Pass A: rowmax of logits ----
    for (int fc = 0; fc < NCHUNK; ++fc) {
        const int fbase = fc * CHUNKF + t * FF;
        const float4 bbA = *(const float4*)(b3 + fbase);
        const float4 bbB = *(const float4*)(b3 + fbase + 4);
        ACC_DECL
        const float* wrow = W3 + fbase;
#pragma unroll 1
        for (int j = 0; j < 64; ++j) JBODY
        ROWMAX(0) ROWMAX(1) ROWMAX(2) ROWMAX(3)
        ROWMAX(4) ROWMAX(5) ROWMAX(6) ROWMAX(7)
    }
    __syncthreads();
    if (t < RROWS) {
        float m = -1e30f;
        for (int fc = 0; fc < NCHUNK; ++fc)
            for (int w = 0; w < 4; ++w) m = fmaxf(m, cm[fc][t][w]);
        thrS[t] = m - 0.1068f;    // gumbel range 0.10581 + fp32 slack
    }
    __syncthreads();

    // ---- Pass B: recompute only qualifying (chunk, wave) cells ----
    float bS0=-1e30f,bS1=-1e30f,bS2=-1e30f,bS3=-1e30f,
          bS4=-1e30f,bS5=-1e30f,bS6=-1e30f,bS7=-1e30f;
    int   bI0=0,bI1=0,bI2=0,bI3=0,bI4=0,bI5=0,bI6=0,bI7=0;

    for (int fc = 0; fc < NCHUNK; ++fc) {
        unsigned qmask = 0;
#pragma unroll
        for (int r = 0; r < RROWS; ++r)
            if (cm[fc][r][wv] >= thrS[r]) qmask |= (1u << r);
        if (qmask == 0) continue;                 // wave-uniform skip

        const int fbase = fc * CHUNKF + t * FF;
        const float4 bbA = *(const float4*)(b3 + fbase);
        const float4 bbB = *(const float4*)(b3 + fbase + 4);
        ACC_DECL
        const float* wrow = W3 + fbase;
#pragma unroll 1
        for (int j = 0; j < 64; ++j) JBODY
        CAND(0) CAND(1) CAND(2) CAND(3)
        CAND(4) CAND(5) CAND(6) CAND(7)
    }

    // reduce best (val, idx) across wave, then across waves
    REDROW(0) REDROW(1) REDROW(2) REDROW(3)
    REDROW(4) REDROW(5) REDROW(6) REDROW(7)
    __syncthreads();
    if (t < RROWS) {
        float v = -1e30f; int ix = 0;
        for (int w = 0; w < 4; ++w) {
            float ov = redS[t][w]; int oi = redI[t][w];
            if (ov > v || (ov == v && oi < ix && ov > -1e29f)) { v = ov; ix = oi; }
        }
        rowInd[t] = ix & (FEATN - 1);   // hard guarantee: in-bounds gather
    }
    __syncthreads();

    // out[b,:] = codebook[ind,:]   (z_st == one-hot to ~1e-7)
    for (int r = 0; r < RROWS; ++r) {
        const int ind = rowInd[r];
        const float4* src = (const float4*)(codebook + (size_t)ind * FDIM);
        float4*       dst = (float4*)(out + (size_t)(b0 + r) * FDIM);
        dst[t] = src[t];
    }
}

// ---------------------------------------------------------------------------
extern "C" void kernel_launch(void* const* d_in, const int* in_sizes, int n_in,
                              void* d_out, int out_size, void* d_ws, size_t ws_size,
                              hipStream_t stream)
{
    const float* x   = (const float*)d_in[0];
    const float* y   = (const float*)d_in[1];
    const float* W1  = (const float*)d_in[2];
    const float* b1  = (const float*)d_in[3];
    const float* g1  = (const float*)d_in[4];
    const float* be1 = (const float*)d_in[5];
    const float* W2  = (const float*)d_in[6];
    const float* b2  = (const float*)d_in[7];
    const float* g2  = (const float*)d_in[8];
    const float* be2 = (const float*)d_in[9];
    const float* W3  = (const float*)d_in[10];
    const float* b3  = (const float*)d_in[11];
    const float* cb  = (const float*)d_in[12];
    float* out = (float*)d_out;

    float* ws  = (float*)d_ws;
    float* a1  = ws;                          // 8192*256 f32
    float* a2  = a1 + B_ROWS * H1;            // 8192*64 f32
    float* sc1 = a2 + B_ROWS * H2;
    float* sh1 = sc1 + H1;
    float* sc2 = sh1 + H1;
    float* sh2 = sc2 + H2;
    double* p1 = (double*)(sh2 + H2 + 64);    // 64*256 f64
    double* p2 = p1 + SLABS * H1;             // 64*256 f64

    k_a1    <<<B_ROWS / 8, 256, 0, stream>>>(x, y, W1, b1, a1);
    k_stats1<<<SLABS, 256, 0, stream>>>(a1, H1, p1, p2);
    k_stats2<<<H1, 64, 0, stream>>>(p1, p2, H1, g1, be1, sc1, sh1);
    k_a2    <<<B_ROWS / 4, 256, 0, stream>>>(a1, sc1, sh1, W2, b2, a2);
    k_stats1<<<SLABS, 256, 0, stream>>>(a2, H2, p1, p2);
    k_stats2<<<H2, 64, 0, stream>>>(p1, p2, H2, g2, be2, sc2, sh2);
    k_main  <<<B_ROWS / RROWS, 256, 0, stream>>>(a2, sc2, sh2, W3, b3, cb, out);
}